// Round 4
// baseline (309.654 us; speedup 1.0000x reference)
//
#include <hip/hip_runtime.h>

#define NB 262144
#define NJ 24
#define TB 256   // batches per block == threads per block

typedef float fvec4 __attribute__((ext_vector_type(4)));
typedef float fvec2 __attribute__((ext_vector_type(2)));

__global__ __launch_bounds__(TB, 5) void fk_kernel(
    const float* __restrict__ rot6,   // [NB][NJ][6]
    const float* __restrict__ pos,    // [NB][NJ][3]
    float* __restrict__ coords,       // [NB][NJ][3]
    float* __restrict__ tf)           // [NB][NJ][4][4]
{
    // One dual-purpose 32 KB buffer:
    //  - staging phase: first 768 fvec4 = rot (48 B/batch), next 768 fvec2 = pos (24 B/batch)
    //  - tile phase: 256 batches x 8 fvec4 (two transforms), XOR-swizzled
    __shared__ fvec4 sbuf[TB * 8];

    const int tid = threadIdx.x;
    const int b0  = blockIdx.x * TB;

    constexpr int P[NJ] = {0,0,0,0,1,2,3,4,5,6,7,8,9,9,9,12,13,14,16,17,18,19,20,21};

    float Gr[NJ][9];   // rotation 3x3, row-major (constant-indexed after unroll)
    float Gt[NJ][3];   // translation

    const fvec4* __restrict__ grot4 = (const fvec4*)rot6;   // 36 f4 / batch
    const fvec2* __restrict__ gpos2 = (const fvec2*)pos;    // 36 f2 / batch
    fvec4* __restrict__ gtf4 = (fvec4*)tf;                  // 96 f4 / batch
    fvec2* __restrict__ gco2 = (fvec2*)coords;              // 36 f2 / batch

    fvec2* spos2 = (fvec2*)(sbuf + TB * 3);  // bytes [12288, 18432)

    #pragma unroll
    for (int t = 0; t < NJ / 2; ++t) {
        // ---- stage inputs (coalesced; cached — we WANT these lines in L2) ----
        #pragma unroll
        for (int i = 0; i < 3; ++i) {
            int q  = i * TB + tid;            // [0, 768)
            int bq = q / 3, kq = q - bq * 3;
            sbuf[q] = grot4[(size_t)(b0 + bq) * 36 + t * 3 + kq];
        }
        #pragma unroll
        for (int i = 0; i < 3; ++i) {
            int q  = i * TB + tid;
            int bq = q / 3, kq = q - bq * 3;
            spos2[q] = gpos2[(size_t)(b0 + bq) * 36 + t * 3 + kq];
        }
        __syncthreads();

        // ---- own-batch fragment LDS -> registers ----
        const fvec4 r0 = sbuf[tid * 3 + 0];
        const fvec4 r1 = sbuf[tid * 3 + 1];
        const fvec4 r2 = sbuf[tid * 3 + 2];
        const fvec2 p0 = spos2[tid * 3 + 0];
        const fvec2 p1 = spos2[tid * 3 + 1];
        const fvec2 p2 = spos2[tid * 3 + 2];
        __syncthreads();   // everyone's inputs in regs before tile overwrites sbuf

        #pragma unroll
        for (int jj = 0; jj < 2; ++jj) {
            const int j = 2 * t + jj;
            const float a1x = jj ? r1.z : r0.x;
            const float a1y = jj ? r1.w : r0.y;
            const float a1z = jj ? r2.x : r0.z;
            const float a2x = jj ? r2.y : r0.w;
            const float a2y = jj ? r2.z : r1.x;
            const float a2z = jj ? r2.w : r1.y;
            const float px  = jj ? p1.y : p0.x;
            const float py  = jj ? p2.x : p0.y;
            const float pz  = jj ? p2.y : p1.x;

            // 6D -> rotation (Gram-Schmidt)
            const float inv1 = rsqrtf(a1x*a1x + a1y*a1y + a1z*a1z);
            const float b1x = a1x*inv1, b1y = a1y*inv1, b1z = a1z*inv1;
            const float d   = b1x*a2x + b1y*a2y + b1z*a2z;
            const float c2x = a2x - d*b1x, c2y = a2y - d*b1y, c2z = a2z - d*b1z;
            const float inv2 = rsqrtf(c2x*c2x + c2y*c2y + c2z*c2z);
            const float b2x = c2x*inv2, b2y = c2y*inv2, b2z = c2z*inv2;
            const float b3x = b1y*b2z - b1z*b2y;
            const float b3y = b1z*b2x - b1x*b2z;
            const float b3z = b1x*b2y - b1y*b2x;

            const float L[9] = { b1x,b1y,b1z, b2x,b2y,b2z, b3x,b3y,b3z };

            if (j == 0) {
                #pragma unroll
                for (int k = 0; k < 9; ++k) Gr[0][k] = L[k];
                Gt[0][0] = px; Gt[0][1] = py; Gt[0][2] = pz;
            } else {
                const int p = P[j];
                #pragma unroll
                for (int r = 0; r < 3; ++r) {
                    const float g0 = Gr[p][r*3+0], g1 = Gr[p][r*3+1], g2 = Gr[p][r*3+2];
                    Gr[j][r*3+0] = g0*L[0] + g1*L[3] + g2*L[6];
                    Gr[j][r*3+1] = g0*L[1] + g1*L[4] + g2*L[7];
                    Gr[j][r*3+2] = g0*L[2] + g1*L[5] + g2*L[8];
                    Gt[j][r]     = g0*px   + g1*py   + g2*pz   + Gt[p][r];
                }
            }

            // transform rows into swizzled LDS tile
            #pragma unroll
            for (int rr = 0; rr < 4; ++rr) {
                const int s = jj * 4 + rr;
                fvec4 v;
                if (rr == 3) { v.x = 0.f; v.y = 0.f; v.z = 0.f; v.w = 1.f; }
                else { v.x = Gr[j][rr*3+0]; v.y = Gr[j][rr*3+1]; v.z = Gr[j][rr*3+2]; v.w = Gt[j][rr]; }
                sbuf[tid * 8 + (s ^ (tid & 7))] = v;
            }
        }

        // coords: cached stores (L2 merges partial lines across phases now that
        // the tf stream bypasses L2)
        {
            const size_t cb = (size_t)(b0 + tid) * 36 + t * 3;
            fvec2 c0; c0.x = Gt[2*t][0];   c0.y = Gt[2*t][1];
            fvec2 c1; c1.x = Gt[2*t][2];   c1.y = Gt[2*t+1][0];
            fvec2 c2; c2.x = Gt[2*t+1][1]; c2.y = Gt[2*t+1][2];
            gco2[cb + 0] = c0;
            gco2[cb + 1] = c1;
            gco2[cb + 2] = c2;
        }

        __syncthreads();

        // ---- flush transforms: wave-contiguous full 128 B lines, NON-TEMPORAL ----
        #pragma unroll
        for (int i = 0; i < 8; ++i) {
            int q  = i * TB + tid;            // [0, 2048)
            int bp = q >> 3, s = q & 7;
            fvec4 v = sbuf[bp * 8 + (s ^ (bp & 7))];
            __builtin_nontemporal_store(v, &gtf4[(size_t)(b0 + bp) * 96 + t * 8 + s]);
        }
        __syncthreads();
    }
}

extern "C" void kernel_launch(void* const* d_in, const int* in_sizes, int n_in,
                              void* d_out, int out_size, void* d_ws, size_t ws_size,
                              hipStream_t stream) {
    const float* rot6 = (const float*)d_in[0];
    const float* pos  = (const float*)d_in[1];
    float* coords = (float*)d_out;                       // B*J*3
    float* tf     = (float*)d_out + (size_t)NB * NJ * 3; // B*J*16

    fk_kernel<<<dim3(NB / TB), dim3(TB), 0, stream>>>(rot6, pos, coords, tf);
}

// Round 6
// 224.039 us; speedup vs baseline: 1.3821x; 1.3821x over previous
//
#include <hip/hip_runtime.h>

#define NB 262144
#define NJ 24
#define TB 256
#define NPH (NJ / 2)

typedef float fvec4 __attribute__((ext_vector_type(4)));
typedef float fvec2 __attribute__((ext_vector_type(2)));

__global__ __launch_bounds__(TB, 2) void fk_kernel(
    const float* __restrict__ rot6,   // [NB][NJ][6]
    const float* __restrict__ pos,    // [NB][NJ][3]
    float* __restrict__ coords,       // [NB][NJ][3]
    float* __restrict__ tf)           // [NB][NJ][4][4]
{
    // LDS (51200 B, same footprint as round 2):
    //   [0,     32768)  stf tile (2048 fvec4)  | epilogue overlay: scoord [72][129] f32
    //   [32768, 45056)  srot (768 fvec4)
    //   [45056, 51200)  spos (768 fvec2)
    __shared__ __align__(16) char smem[51200];
    fvec4* stf    = (fvec4*)smem;
    fvec4* srot   = (fvec4*)(smem + 32768);
    fvec2* spos   = (fvec2*)(smem + 45056);
    float* scoord = (float*)smem;

    const int tid = threadIdx.x;
    const int b0  = blockIdx.x * TB;

    constexpr int P[NJ] = {0,0,0,0,1,2,3,4,5,6,7,8,9,9,9,12,13,14,16,17,18,19,20,21};

    float Gr[NJ][9];   // rotation 3x3 (constant-indexed; frontier-live only)
    float Gt[NJ][3];   // translation — ALL live until epilogue (register-resident coords)

    const fvec4* __restrict__ grot4 = (const fvec4*)rot6;   // 36 fvec4 / batch
    const fvec2* __restrict__ gpos2 = (const fvec2*)pos;    // 36 fvec2 / batch
    fvec4* __restrict__ gtf4 = (fvec4*)tf;                  // 96 fvec4 / batch
    fvec4* __restrict__ gco4 = (fvec4*)coords;              // 18 fvec4 / batch

    #pragma unroll
    for (int t = 0; t < NPH; ++t) {
        // ---- stage inputs (coalesced; identical to round 2) ----
        #pragma unroll
        for (int i = 0; i < 3; ++i) {
            int q  = i * TB + tid;            // [0, 768)
            int bq = q / 3, kq = q - bq * 3;
            srot[q] = grot4[(size_t)(b0 + bq) * 36 + t * 3 + kq];
        }
        #pragma unroll
        for (int i = 0; i < 3; ++i) {
            int q  = i * TB + tid;
            int bq = q / 3, kq = q - bq * 3;
            spos[q] = gpos2[(size_t)(b0 + bq) * 36 + t * 3 + kq];
        }
        __syncthreads();

        // ---- own-batch fragment LDS -> registers ----
        const fvec4 r0 = srot[tid * 3 + 0];
        const fvec4 r1 = srot[tid * 3 + 1];
        const fvec4 r2 = srot[tid * 3 + 2];
        const fvec2 p0 = spos[tid * 3 + 0];
        const fvec2 p1 = spos[tid * 3 + 1];
        const fvec2 p2 = spos[tid * 3 + 2];

        #pragma unroll
        for (int jj = 0; jj < 2; ++jj) {
            const int j = 2 * t + jj;
            const float a1x = jj ? r1.z : r0.x;
            const float a1y = jj ? r1.w : r0.y;
            const float a1z = jj ? r2.x : r0.z;
            const float a2x = jj ? r2.y : r0.w;
            const float a2y = jj ? r2.z : r1.x;
            const float a2z = jj ? r2.w : r1.y;
            const float px  = jj ? p1.y : p0.x;
            const float py  = jj ? p2.x : p0.y;
            const float pz  = jj ? p2.y : p1.x;

            // 6D -> rotation (Gram-Schmidt)
            const float inv1 = rsqrtf(a1x*a1x + a1y*a1y + a1z*a1z);
            const float b1x = a1x*inv1, b1y = a1y*inv1, b1z = a1z*inv1;
            const float d   = b1x*a2x + b1y*a2y + b1z*a2z;
            const float c2x = a2x - d*b1x, c2y = a2y - d*b1y, c2z = a2z - d*b1z;
            const float inv2 = rsqrtf(c2x*c2x + c2y*c2y + c2z*c2z);
            const float b2x = c2x*inv2, b2y = c2y*inv2, b2z = c2z*inv2;
            const float b3x = b1y*b2z - b1z*b2y;
            const float b3y = b1z*b2x - b1x*b2z;
            const float b3z = b1x*b2y - b1y*b2x;

            const float L[9] = { b1x,b1y,b1z, b2x,b2y,b2z, b3x,b3y,b3z };

            if (j == 0) {
                #pragma unroll
                for (int k = 0; k < 9; ++k) Gr[0][k] = L[k];
                Gt[0][0] = px; Gt[0][1] = py; Gt[0][2] = pz;
            } else {
                const int p = P[j];
                #pragma unroll
                for (int r = 0; r < 3; ++r) {
                    const float g0 = Gr[p][r*3+0], g1 = Gr[p][r*3+1], g2 = Gr[p][r*3+2];
                    Gr[j][r*3+0] = g0*L[0] + g1*L[3] + g2*L[6];
                    Gr[j][r*3+1] = g0*L[1] + g1*L[4] + g2*L[7];
                    Gr[j][r*3+2] = g0*L[2] + g1*L[5] + g2*L[8];
                    Gt[j][r]     = g0*px   + g1*py   + g2*pz   + Gt[p][r];
                }
            }

            // transform rows into swizzled LDS tile
            #pragma unroll
            for (int rr = 0; rr < 4; ++rr) {
                const int s = jj * 4 + rr;
                fvec4 v;
                if (rr == 3) { v.x = 0.f; v.y = 0.f; v.z = 0.f; v.w = 1.f; }
                else { v.x = Gr[j][rr*3+0]; v.y = Gr[j][rr*3+1]; v.z = Gr[j][rr*3+2]; v.w = Gt[j][rr]; }
                stf[tid * 8 + (s ^ (tid & 7))] = v;
            }
        }

        __syncthreads();

        // ---- flush transforms: wave-contiguous full 128 B lines ----
        #pragma unroll
        for (int i = 0; i < 8; ++i) {
            int q  = i * TB + tid;
            int bp = q >> 3, s = q & 7;
            fvec4 v = stf[bp * 8 + (s ^ (bp & 7))];
            gtf4[(size_t)(b0 + bp) * 96 + t * 8 + s] = v;
        }
        __syncthreads();
    }

    // ---- epilogue: coords via LDS transpose (overlay on stf), full-line writes ----
    #pragma unroll
    for (int h = 0; h < 2; ++h) {
        if ((tid >> 7) == h) {
            const int bl = tid & 127;
            #pragma unroll
            for (int j = 0; j < NJ; ++j)
                #pragma unroll
                for (int r = 0; r < 3; ++r)
                    scoord[(j * 3 + r) * 129 + bl] = Gt[j][r];
        }
        __syncthreads();
        #pragma unroll
        for (int i = 0; i < 9; ++i) {
            int fq = i * TB + tid;            // [0, 2304) = 128 batches x 18 fvec4
            int br = fq / 18, k = fq - br * 18;
            fvec4 v;
            v.x = scoord[(4 * k + 0) * 129 + br];
            v.y = scoord[(4 * k + 1) * 129 + br];
            v.z = scoord[(4 * k + 2) * 129 + br];
            v.w = scoord[(4 * k + 3) * 129 + br];
            gco4[(size_t)(b0 + h * 128 + br) * 18 + k] = v;
        }
        __syncthreads();
    }
}

extern "C" void kernel_launch(void* const* d_in, const int* in_sizes, int n_in,
                              void* d_out, int out_size, void* d_ws, size_t ws_size,
                              hipStream_t stream) {
    const float* rot6 = (const float*)d_in[0];
    const float* pos  = (const float*)d_in[1];
    float* coords = (float*)d_out;                       // B*J*3
    float* tf     = (float*)d_out + (size_t)NB * NJ * 3; // B*J*16

    fk_kernel<<<dim3(NB / TB), dim3(TB), 0, stream>>>(rot6, pos, coords, tf);
}

// Round 7
// 207.006 us; speedup vs baseline: 1.4959x; 1.0823x over previous
//
#include <hip/hip_runtime.h>

#define NB 262144
#define NJ 24
#define TB 256
#define NPH (NJ / 2)

typedef float fvec4 __attribute__((ext_vector_type(4)));
typedef float fvec2 __attribute__((ext_vector_type(2)));

__global__ __launch_bounds__(TB, 2) void fk_kernel(
    const float* __restrict__ rot6,   // [NB][NJ][6]
    const float* __restrict__ pos,    // [NB][NJ][3]
    float* __restrict__ coords,       // [NB][NJ][3]
    float* __restrict__ tf)           // [NB][NJ][4][4]
{
    // LDS map (69632 B):
    //   [0,     32768)  stf tile (2048 fvec4) | epilogue overlay: scoord [72][129] f32 (37164 B, spills into srot area — only used after all phases)
    //   [32768, 57344)  srot[2][768] fvec4  (double-buffered staging)
    //   [57344, 69632)  spos[2][768] fvec2
    __shared__ __align__(16) char smem[69632];
    fvec4* stf    = (fvec4*)smem;
    fvec4* srot0  = (fvec4*)(smem + 32768);
    fvec4* srot1  = (fvec4*)(smem + 45056);
    fvec2* spos0  = (fvec2*)(smem + 57344);
    fvec2* spos1  = (fvec2*)(smem + 63488);
    float* scoord = (float*)smem;

    const int tid = threadIdx.x;
    const int b0  = blockIdx.x * TB;

    constexpr int P[NJ] = {0,0,0,0,1,2,3,4,5,6,7,8,9,9,9,12,13,14,16,17,18,19,20,21};

    float Gr[NJ][9];   // rotation 3x3 (constant-indexed; frontier-live only)
    float Gt[NJ][3];   // translation — ALL live until epilogue

    const fvec4* __restrict__ grot4 = (const fvec4*)rot6;   // 36 fvec4 / batch
    const fvec2* __restrict__ gpos2 = (const fvec2*)pos;    // 36 fvec2 / batch
    fvec4* __restrict__ gtf4 = (fvec4*)tf;                  // 96 fvec4 / batch
    fvec4* __restrict__ gco4 = (fvec4*)coords;              // 18 fvec4 / batch

    // q-linear staging mapping for this thread (compile-time per i)
    int bq_[3], kq_[3];
    #pragma unroll
    for (int i = 0; i < 3; ++i) {
        int q = i * TB + tid;
        bq_[i] = q / 3; kq_[i] = q - bq_[i] * 3;
    }

    // ---- prologue: stage phase 0 through registers ----
    fvec4 pr0, pr1, pr2; fvec2 pp0, pp1, pp2;
    {
        pr0 = grot4[(size_t)(b0 + bq_[0]) * 36 + 0 * 3 + kq_[0]];
        pr1 = grot4[(size_t)(b0 + bq_[1]) * 36 + 0 * 3 + kq_[1]];
        pr2 = grot4[(size_t)(b0 + bq_[2]) * 36 + 0 * 3 + kq_[2]];
        pp0 = gpos2[(size_t)(b0 + bq_[0]) * 36 + 0 * 3 + kq_[0]];
        pp1 = gpos2[(size_t)(b0 + bq_[1]) * 36 + 0 * 3 + kq_[1]];
        pp2 = gpos2[(size_t)(b0 + bq_[2]) * 36 + 0 * 3 + kq_[2]];
        srot0[0 * TB + tid] = pr0;  srot0[1 * TB + tid] = pr1;  srot0[2 * TB + tid] = pr2;
        spos0[0 * TB + tid] = pp0;  spos0[1 * TB + tid] = pp1;  spos0[2 * TB + tid] = pp2;
    }

    #pragma unroll
    for (int t = 0; t < NPH; ++t) {
        __syncthreads();   // staging for phase t visible (and prior flush reads done)

        // ---- issue prefetch loads for phase t+1 (latency hides under compute+flush) ----
        if (t + 1 < NPH) {
            pr0 = grot4[(size_t)(b0 + bq_[0]) * 36 + (t + 1) * 3 + kq_[0]];
            pr1 = grot4[(size_t)(b0 + bq_[1]) * 36 + (t + 1) * 3 + kq_[1]];
            pr2 = grot4[(size_t)(b0 + bq_[2]) * 36 + (t + 1) * 3 + kq_[2]];
            pp0 = gpos2[(size_t)(b0 + bq_[0]) * 36 + (t + 1) * 3 + kq_[0]];
            pp1 = gpos2[(size_t)(b0 + bq_[1]) * 36 + (t + 1) * 3 + kq_[1]];
            pp2 = gpos2[(size_t)(b0 + bq_[2]) * 36 + (t + 1) * 3 + kq_[2]];
        }

        // ---- own-batch fragment LDS -> registers ----
        const fvec4* srot = (t & 1) ? srot1 : srot0;
        const fvec2* spos = (t & 1) ? spos1 : spos0;
        const fvec4 r0 = srot[tid * 3 + 0];
        const fvec4 r1 = srot[tid * 3 + 1];
        const fvec4 r2 = srot[tid * 3 + 2];
        const fvec2 p0 = spos[tid * 3 + 0];
        const fvec2 p1 = spos[tid * 3 + 1];
        const fvec2 p2 = spos[tid * 3 + 2];

        #pragma unroll
        for (int jj = 0; jj < 2; ++jj) {
            const int j = 2 * t + jj;
            const float a1x = jj ? r1.z : r0.x;
            const float a1y = jj ? r1.w : r0.y;
            const float a1z = jj ? r2.x : r0.z;
            const float a2x = jj ? r2.y : r0.w;
            const float a2y = jj ? r2.z : r1.x;
            const float a2z = jj ? r2.w : r1.y;
            const float px  = jj ? p1.y : p0.x;
            const float py  = jj ? p2.x : p0.y;
            const float pz  = jj ? p2.y : p1.x;

            // 6D -> rotation (Gram-Schmidt)
            const float inv1 = rsqrtf(a1x*a1x + a1y*a1y + a1z*a1z);
            const float b1x = a1x*inv1, b1y = a1y*inv1, b1z = a1z*inv1;
            const float d   = b1x*a2x + b1y*a2y + b1z*a2z;
            const float c2x = a2x - d*b1x, c2y = a2y - d*b1y, c2z = a2z - d*b1z;
            const float inv2 = rsqrtf(c2x*c2x + c2y*c2y + c2z*c2z);
            const float b2x = c2x*inv2, b2y = c2y*inv2, b2z = c2z*inv2;
            const float b3x = b1y*b2z - b1z*b2y;
            const float b3y = b1z*b2x - b1x*b2z;
            const float b3z = b1x*b2y - b1y*b2x;

            const float L[9] = { b1x,b1y,b1z, b2x,b2y,b2z, b3x,b3y,b3z };

            if (j == 0) {
                #pragma unroll
                for (int k = 0; k < 9; ++k) Gr[0][k] = L[k];
                Gt[0][0] = px; Gt[0][1] = py; Gt[0][2] = pz;
            } else {
                const int p = P[j];
                #pragma unroll
                for (int r = 0; r < 3; ++r) {
                    const float g0 = Gr[p][r*3+0], g1 = Gr[p][r*3+1], g2 = Gr[p][r*3+2];
                    Gr[j][r*3+0] = g0*L[0] + g1*L[3] + g2*L[6];
                    Gr[j][r*3+1] = g0*L[1] + g1*L[4] + g2*L[7];
                    Gr[j][r*3+2] = g0*L[2] + g1*L[5] + g2*L[8];
                    Gt[j][r]     = g0*px   + g1*py   + g2*pz   + Gt[p][r];
                }
            }

            // transform rows into swizzled LDS tile
            #pragma unroll
            for (int rr = 0; rr < 4; ++rr) {
                const int s = jj * 4 + rr;
                fvec4 v;
                if (rr == 3) { v.x = 0.f; v.y = 0.f; v.z = 0.f; v.w = 1.f; }
                else { v.x = Gr[j][rr*3+0]; v.y = Gr[j][rr*3+1]; v.z = Gr[j][rr*3+2]; v.w = Gt[j][rr]; }
                stf[tid * 8 + (s ^ (tid & 7))] = v;
            }
        }

        __syncthreads();   // stf tile visible; frag reads of buf(t&1) complete

        // ---- flush transforms: wave-contiguous full 128 B lines ----
        #pragma unroll
        for (int i = 0; i < 8; ++i) {
            int q  = i * TB + tid;
            int bp = q >> 3, s = q & 7;
            fvec4 v = stf[bp * 8 + (s ^ (bp & 7))];
            gtf4[(size_t)(b0 + bp) * 96 + t * 8 + s] = v;
        }

        // ---- write prefetched inputs into the alternate staging buffer ----
        if (t + 1 < NPH) {
            fvec4* nrot = (t & 1) ? srot0 : srot1;
            fvec2* npos = (t & 1) ? spos0 : spos1;
            nrot[0 * TB + tid] = pr0;  nrot[1 * TB + tid] = pr1;  nrot[2 * TB + tid] = pr2;
            npos[0 * TB + tid] = pp0;  npos[1 * TB + tid] = pp1;  npos[2 * TB + tid] = pp2;
        }
    }
    __syncthreads();   // flush reads of stf done before scoord overlay

    // ---- epilogue: coords via LDS transpose (overlay), full-line writes ----
    #pragma unroll
    for (int h = 0; h < 2; ++h) {
        if ((tid >> 7) == h) {
            const int bl = tid & 127;
            #pragma unroll
            for (int j = 0; j < NJ; ++j)
                #pragma unroll
                for (int r = 0; r < 3; ++r)
                    scoord[(j * 3 + r) * 129 + bl] = Gt[j][r];
        }
        __syncthreads();
        #pragma unroll
        for (int i = 0; i < 9; ++i) {
            int fq = i * TB + tid;            // [0, 2304) = 128 batches x 18 fvec4
            int br = fq / 18, k = fq - br * 18;
            fvec4 v;
            v.x = scoord[(4 * k + 0) * 129 + br];
            v.y = scoord[(4 * k + 1) * 129 + br];
            v.z = scoord[(4 * k + 2) * 129 + br];
            v.w = scoord[(4 * k + 3) * 129 + br];
            gco4[(size_t)(b0 + h * 128 + br) * 18 + k] = v;
        }
        __syncthreads();
    }
}

extern "C" void kernel_launch(void* const* d_in, const int* in_sizes, int n_in,
                              void* d_out, int out_size, void* d_ws, size_t ws_size,
                              hipStream_t stream) {
    const float* rot6 = (const float*)d_in[0];
    const float* pos  = (const float*)d_in[1];
    float* coords = (float*)d_out;                       // B*J*3
    float* tf     = (float*)d_out + (size_t)NB * NJ * 3; // B*J*16

    fk_kernel<<<dim3(NB / TB), dim3(TB), 0, stream>>>(rot6, pos, coords, tf);
}

// Round 8
// 142.592 us; speedup vs baseline: 2.1716x; 1.4517x over previous
//
#include <hip/hip_runtime.h>

#define NB 262144
#define NJ 24
#define TB 256
#define NBATCH 64          // batches per block; 4 threads (rows) per batch
#define NPH (NJ / 2)

typedef float fvec4 __attribute__((ext_vector_type(4)));
typedef float fvec2 __attribute__((ext_vector_type(2)));

__global__ __launch_bounds__(TB, 2) void fk_kernel(
    const float* __restrict__ rot6,   // [NB][NJ][6]
    const float* __restrict__ pos,    // [NB][NJ][3]
    float* __restrict__ coords,       // [NB][NJ][3]
    float* __restrict__ tf)           // [NB][NJ][4][4]
{
    // LDS map (71680 B):
    //   [0,     36864)  sin_rot fvec4[2304]  phase-major [12 t][64 bl][3 k]
    //                   | epilogue overlay: scoord [64][73] floats (18688 B)
    //   [36864, 55296)  sin_pos fvec2[2304]  [12 t][64 bl][3 k]
    //   [55296, 71680)  stf fvec4[2][512]    double-buffered tile [64 bl][8 s]
    __shared__ __align__(16) char smem[71680];
    fvec4* sin_rot = (fvec4*)smem;
    fvec2* sin_pos = (fvec2*)(smem + 36864);
    fvec4* stf     = (fvec4*)(smem + 55296);
    float* scoord  = (float*)smem;

    const int tid = threadIdx.x;
    const int bl  = tid & 63;     // batch within block (== lane)
    const int r   = tid >> 6;     // row 0..3 (== wave)
    const int b0  = blockIdx.x * NBATCH;

    constexpr int P[NJ] = {0,0,0,0,1,2,3,4,5,6,7,8,9,9,9,12,13,14,16,17,18,19,20,21};

    const fvec4* __restrict__ grot4 = (const fvec4*)rot6;   // 36 fvec4 / batch
    const fvec2* __restrict__ gpos2 = (const fvec2*)pos;    // 36 fvec2 / batch
    fvec4* __restrict__ gtf4 = (fvec4*)tf;                  // 96 fvec4 / batch
    fvec2* __restrict__ gco2 = (fvec2*)coords;              // 36 fvec2 / batch

    // ---- one-shot input staging: perfectly linear global sweep, zero refetch ----
    #pragma unroll
    for (int i = 0; i < 9; ++i) {
        int q  = i * TB + tid;                 // [0, 2304) fvec4
        int bq = q / 36, rem = q - bq * 36;    // batch, fvec4-within-batch
        int t  = rem / 3, k = rem - t * 3;     // phase, fvec4-within-phase
        sin_rot[t * 192 + bq * 3 + k] = grot4[(size_t)(b0 + bq) * 36 + rem];
    }
    #pragma unroll
    for (int i = 0; i < 9; ++i) {
        int q  = i * TB + tid;                 // [0, 2304) fvec2
        int bq = q / 36, rem = q - bq * 36;
        int t  = rem / 3, k = rem - t * 3;
        sin_pos[t * 192 + bq * 3 + k] = gpos2[(size_t)(b0 + bq) * 36 + rem];
    }
    __syncthreads();

    // this thread's row r of G[j]; [0..2] frontier-live, [3] (=w) lives to epilogue
    float Grow[NJ][4];

    #pragma unroll
    for (int t = 0; t < NPH; ++t) {
        // own-batch fragment (stride 48 B / 24 B across lanes: conflict-free)
        const fvec4 r0 = sin_rot[t * 192 + bl * 3 + 0];
        const fvec4 r1 = sin_rot[t * 192 + bl * 3 + 1];
        const fvec4 r2 = sin_rot[t * 192 + bl * 3 + 2];
        const fvec2 p0 = sin_pos[t * 192 + bl * 3 + 0];
        const fvec2 p1 = sin_pos[t * 192 + bl * 3 + 1];
        const fvec2 p2 = sin_pos[t * 192 + bl * 3 + 2];
        fvec4* tile = stf + (t & 1) * 512;

        #pragma unroll
        for (int jj = 0; jj < 2; ++jj) {
            const int j = 2 * t + jj;
            const float a1x = jj ? r1.z : r0.x;
            const float a1y = jj ? r1.w : r0.y;
            const float a1z = jj ? r2.x : r0.z;
            const float a2x = jj ? r2.y : r0.w;
            const float a2y = jj ? r2.z : r1.x;
            const float a2z = jj ? r2.w : r1.y;
            const float px  = jj ? p1.y : p0.x;
            const float py  = jj ? p2.x : p0.y;
            const float pz  = jj ? p2.y : p1.x;

            // 6D -> rotation (Gram-Schmidt), redundantly per row-thread (VALU is idle)
            const float inv1 = rsqrtf(a1x*a1x + a1y*a1y + a1z*a1z);
            const float b1x = a1x*inv1, b1y = a1y*inv1, b1z = a1z*inv1;
            const float d   = b1x*a2x + b1y*a2y + b1z*a2z;
            const float c2x = a2x - d*b1x, c2y = a2y - d*b1y, c2z = a2z - d*b1z;
            const float inv2 = rsqrtf(c2x*c2x + c2y*c2y + c2z*c2z);
            const float b2x = c2x*inv2, b2y = c2y*inv2, b2z = c2z*inv2;
            const float b3x = b1y*b2z - b1z*b2y;
            const float b3y = b1z*b2x - b1x*b2z;
            const float b3z = b1x*b2y - b1y*b2x;

            fvec4 out;
            if (j == 0) {
                // row select; r==3 -> (0,0,0,1), preserved by the update math forever
                out.x = (r == 0) ? b1x : (r == 1) ? b2x : (r == 2) ? b3x : 0.f;
                out.y = (r == 0) ? b1y : (r == 1) ? b2y : (r == 2) ? b3y : 0.f;
                out.z = (r == 0) ? b1z : (r == 1) ? b2z : (r == 2) ? b3z : 0.f;
                out.w = (r == 0) ? px  : (r == 1) ? py  : (r == 2) ? pz  : 1.f;
            } else {
                const int p = P[j];
                const float g0 = Grow[p][0], g1 = Grow[p][1], g2 = Grow[p][2], g3 = Grow[p][3];
                out.x = g0*b1x + g1*b2x + g2*b3x;
                out.y = g0*b1y + g1*b2y + g2*b3y;
                out.z = g0*b1z + g1*b2z + g2*b3z;
                out.w = g0*px  + g1*py  + g2*pz  + g3;
            }
            Grow[j][0] = out.x; Grow[j][1] = out.y;
            Grow[j][2] = out.z; Grow[j][3] = out.w;

            // row into swizzled tile (64 lanes spread evenly over 8 quad-cols)
            tile[bl * 8 + ((jj * 4 + r) ^ (bl & 7))] = out;
        }

        __syncthreads();   // tile complete; also retires prev flush's LDS reads

        // flush: 8 KB = 64 full 128-B lines, wave-contiguous
        #pragma unroll
        for (int i = 0; i < 2; ++i) {
            int q  = i * TB + tid;            // [0, 512)
            int bp = q >> 3, s = q & 7;
            fvec4 v = tile[bp * 8 + (s ^ (bp & 7))];
            gtf4[(size_t)(b0 + bp) * 96 + t * 8 + s] = v;
        }
        // no barrier: next phase writes the other tile buffer
    }
    __syncthreads();   // all sin reads done before scoord overlay

    // ---- epilogue: coords. Per-block output is PERFECTLY linear (18432 B) ----
    if (r < 3) {
        #pragma unroll
        for (int j = 0; j < NJ; ++j)
            scoord[bl * 73 + j * 3 + r] = Grow[j][3];   // stride 73: bank-free
    }
    __syncthreads();
    #pragma unroll
    for (int i = 0; i < 9; ++i) {
        int fq = i * TB + tid;                // [0, 2304) fvec2
        int br = fq / 36, k2 = fq - br * 36;
        fvec2 v;
        v.x = scoord[br * 73 + 2 * k2 + 0];
        v.y = scoord[br * 73 + 2 * k2 + 1];
        gco2[(size_t)(b0 + br) * 36 + k2] = v;
    }
}

extern "C" void kernel_launch(void* const* d_in, const int* in_sizes, int n_in,
                              void* d_out, int out_size, void* d_ws, size_t ws_size,
                              hipStream_t stream) {
    const float* rot6 = (const float*)d_in[0];
    const float* pos  = (const float*)d_in[1];
    float* coords = (float*)d_out;                       // B*J*3
    float* tf     = (float*)d_out + (size_t)NB * NJ * 3; // B*J*16

    fk_kernel<<<dim3(NB / NBATCH), dim3(TB), 0, stream>>>(rot6, pos, coords, tf);
}

// Round 9
// 138.236 us; speedup vs baseline: 2.2400x; 1.0315x over previous
//
#include <hip/hip_runtime.h>

#define NB 262144
#define NJ 24
#define TB 128
#define NBATCH 32          // batches per block; 4 threads (rows) per batch
#define NPH (NJ / 2)

typedef float fvec4 __attribute__((ext_vector_type(4)));
typedef float fvec2 __attribute__((ext_vector_type(2)));

__global__ __launch_bounds__(TB, 2) void fk_kernel(
    const float* __restrict__ rot6,   // [NB][NJ][6]
    const float* __restrict__ pos,    // [NB][NJ][3]
    float* __restrict__ coords,       // [NB][NJ][3]
    float* __restrict__ tf)           // [NB][NJ][4][4]
{
    // LDS map (35840 B -> 4 blocks/CU):
    //   [0,     18432)  sin_rot fvec4[1152]  phase-major [12 t][32 bl][3 k]
    //                   | epilogue overlay: scoord [32][73] floats (9344 B)
    //   [18432, 27648)  sin_pos fvec2[1152]  [12 t][32 bl][3 k]
    //   [27648, 35840)  stf fvec4[2][256]    double-buffered tile [32 bl][8 s]
    __shared__ __align__(16) char smem[35840];
    fvec4* sin_rot = (fvec4*)smem;
    fvec2* sin_pos = (fvec2*)(smem + 18432);
    fvec4* stf     = (fvec4*)(smem + 27648);
    float* scoord  = (float*)smem;

    const int tid = threadIdx.x;
    const int bl  = tid & 31;     // batch within block
    const int r   = tid >> 5;     // row 0..3
    const int b0  = blockIdx.x * NBATCH;

    constexpr int P[NJ] = {0,0,0,0,1,2,3,4,5,6,7,8,9,9,9,12,13,14,16,17,18,19,20,21};

    const fvec4* __restrict__ grot4 = (const fvec4*)rot6;   // 36 fvec4 / batch
    const fvec2* __restrict__ gpos2 = (const fvec2*)pos;    // 36 fvec2 / batch
    fvec4* __restrict__ gtf4 = (fvec4*)tf;                  // 96 fvec4 / batch
    fvec2* __restrict__ gco2 = (fvec2*)coords;              // 36 fvec2 / batch

    // ---- one-shot input staging: perfectly linear global sweep, zero refetch ----
    #pragma unroll
    for (int i = 0; i < 9; ++i) {
        int q  = i * TB + tid;                 // [0, 1152) fvec4
        int bq = q / 36, rem = q - bq * 36;    // batch, fvec4-within-batch
        int t  = rem / 3, k = rem - t * 3;     // phase, fvec4-within-phase
        sin_rot[t * 96 + bq * 3 + k] = grot4[(size_t)(b0 + bq) * 36 + rem];
    }
    #pragma unroll
    for (int i = 0; i < 9; ++i) {
        int q  = i * TB + tid;                 // [0, 1152) fvec2
        int bq = q / 36, rem = q - bq * 36;
        int t  = rem / 3, k = rem - t * 3;
        sin_pos[t * 96 + bq * 3 + k] = gpos2[(size_t)(b0 + bq) * 36 + rem];
    }
    __syncthreads();

    // this thread's row r of G[j]; [0..2] frontier-live, [3] (=w) lives to epilogue
    float Grow[NJ][4];

    #pragma unroll
    for (int t = 0; t < NPH; ++t) {
        // own-batch fragment (stride 48 B / 24 B across lanes: uniform bank spread)
        const fvec4 r0 = sin_rot[t * 96 + bl * 3 + 0];
        const fvec4 r1 = sin_rot[t * 96 + bl * 3 + 1];
        const fvec4 r2 = sin_rot[t * 96 + bl * 3 + 2];
        const fvec2 p0 = sin_pos[t * 96 + bl * 3 + 0];
        const fvec2 p1 = sin_pos[t * 96 + bl * 3 + 1];
        const fvec2 p2 = sin_pos[t * 96 + bl * 3 + 2];
        fvec4* tile = stf + (t & 1) * 256;

        #pragma unroll
        for (int jj = 0; jj < 2; ++jj) {
            const int j = 2 * t + jj;
            const float a1x = jj ? r1.z : r0.x;
            const float a1y = jj ? r1.w : r0.y;
            const float a1z = jj ? r2.x : r0.z;
            const float a2x = jj ? r2.y : r0.w;
            const float a2y = jj ? r2.z : r1.x;
            const float a2z = jj ? r2.w : r1.y;
            const float px  = jj ? p1.y : p0.x;
            const float py  = jj ? p2.x : p0.y;
            const float pz  = jj ? p2.y : p1.x;

            // 6D -> rotation (Gram-Schmidt), redundantly per row-thread (VALU has slack)
            const float inv1 = rsqrtf(a1x*a1x + a1y*a1y + a1z*a1z);
            const float b1x = a1x*inv1, b1y = a1y*inv1, b1z = a1z*inv1;
            const float d   = b1x*a2x + b1y*a2y + b1z*a2z;
            const float c2x = a2x - d*b1x, c2y = a2y - d*b1y, c2z = a2z - d*b1z;
            const float inv2 = rsqrtf(c2x*c2x + c2y*c2y + c2z*c2z);
            const float b2x = c2x*inv2, b2y = c2y*inv2, b2z = c2z*inv2;
            const float b3x = b1y*b2z - b1z*b2y;
            const float b3y = b1z*b2x - b1x*b2z;
            const float b3z = b1x*b2y - b1y*b2x;

            fvec4 out;
            if (j == 0) {
                // row select; r==3 -> (0,0,0,1), preserved by the update math forever
                out.x = (r == 0) ? b1x : (r == 1) ? b2x : (r == 2) ? b3x : 0.f;
                out.y = (r == 0) ? b1y : (r == 1) ? b2y : (r == 2) ? b3y : 0.f;
                out.z = (r == 0) ? b1z : (r == 1) ? b2z : (r == 2) ? b3z : 0.f;
                out.w = (r == 0) ? px  : (r == 1) ? py  : (r == 2) ? pz  : 1.f;
            } else {
                const int p = P[j];
                const float g0 = Grow[p][0], g1 = Grow[p][1], g2 = Grow[p][2], g3 = Grow[p][3];
                out.x = g0*b1x + g1*b2x + g2*b3x;
                out.y = g0*b1y + g1*b2y + g2*b3y;
                out.z = g0*b1z + g1*b2z + g2*b3z;
                out.w = g0*px  + g1*py  + g2*pz  + g3;
            }
            Grow[j][0] = out.x; Grow[j][1] = out.y;
            Grow[j][2] = out.z; Grow[j][3] = out.w;

            // row into swizzled tile (uniform quad-bank spread per wave)
            tile[bl * 8 + ((jj * 4 + r) ^ (bl & 7))] = out;
        }

        __syncthreads();   // tile complete; also retires prev flush's LDS reads

        // flush: 4 KB = 32 full 128-B lines, wave-contiguous
        #pragma unroll
        for (int i = 0; i < 2; ++i) {
            int q  = i * TB + tid;            // [0, 256)
            int bp = q >> 3, s = q & 7;
            fvec4 v = tile[bp * 8 + (s ^ (bp & 7))];
            gtf4[(size_t)(b0 + bp) * 96 + t * 8 + s] = v;
        }
        // no barrier: next phase writes the other tile buffer
    }
    __syncthreads();   // all sin reads done before scoord overlay

    // ---- epilogue: coords. Per-block output is perfectly linear (9216 B) ----
    if (r < 3) {
        #pragma unroll
        for (int j = 0; j < NJ; ++j)
            scoord[bl * 73 + j * 3 + r] = Grow[j][3];   // stride 73: bank-free
    }
    __syncthreads();
    #pragma unroll
    for (int i = 0; i < 9; ++i) {
        int fq = i * TB + tid;                // [0, 1152) fvec2
        int br = fq / 36, k2 = fq - br * 36;
        fvec2 v;
        v.x = scoord[br * 73 + 2 * k2 + 0];
        v.y = scoord[br * 73 + 2 * k2 + 1];
        gco2[(size_t)(b0 + br) * 36 + k2] = v;
    }
}

extern "C" void kernel_launch(void* const* d_in, const int* in_sizes, int n_in,
                              void* d_out, int out_size, void* d_ws, size_t ws_size,
                              hipStream_t stream) {
    const float* rot6 = (const float*)d_in[0];
    const float* pos  = (const float*)d_in[1];
    float* coords = (float*)d_out;                       // B*J*3
    float* tf     = (float*)d_out + (size_t)NB * NJ * 3; // B*J*16

    fk_kernel<<<dim3(NB / NBATCH), dim3(TB), 0, stream>>>(rot6, pos, coords, tf);
}